// Round 3
// baseline (411.474 us; speedup 1.0000x reference)
//
#include <hip/hip_runtime.h>

#define KCB    512
#define CHUNK  128
#define P      68      // LDS row stride (floats): rows 16B-aligned for b128, <=2-way bank overlap
#define EPS    0.008f  // > 2x worst-case fp32 distance error

__global__ __launch_bounds__(256, 2) void vq_kernel(
    const float* __restrict__ x, const float* __restrict__ emb,
    float* __restrict__ out_q, float* __restrict__ out_enc,
    float* __restrict__ out_dist, float* __restrict__ out_loss)
{
    __shared__ float xs[128 * P];      // x tile   [row][d], row = hh*64 + w
    __shared__ float es[CHUNK * P];    // emb tile [k][d]
    __shared__ float xx_s[128];        // ||x_n||^2
    __shared__ float ee_s[CHUNK];      // ||e_k||^2 (per chunk)
    __shared__ int   enc_s[128];
    __shared__ float red_s[4];

    const int t   = threadIdx.x;
    const int bid = blockIdx.x;            // 1024 blocks x 128 rows
    const int n_base = bid * 128;
    const int b   = bid >> 5;
    const int h0  = (bid & 31) * 2;        // two h values per block
    const size_t xb0 = (size_t)b * 262144 + (size_t)h0 * 64;   // + d*4096 + hh*64 + w

    // ---- stage x tile (coalesced: lanes sweep w) ----
    {
        const int w = t & 63;
        const int q = t >> 6;              // 0..3
        #pragma unroll
        for (int it = 0; it < 32; ++it) {
            int idx = q + it * 4;          // 0..127 = hh*64 + d
            int hh = idx >> 6, d = idx & 63;
            xs[(hh * 64 + w) * P + d] = x[xb0 + (size_t)d * 4096 + hh * 64 + w];
        }
    }
    __syncthreads();
    if (t < 128) {
        float s = 0.f;
        #pragma unroll
        for (int d = 0; d < 64; ++d) { float v = xs[t * P + d]; s = fmaf(v, v, s); }
        xx_s[t] = s;
    }

    const int tx = t & 15;                 // k-lane (16): k = kc*128 + tx + 16*j
    const int ty = t >> 4;                 // n-group (16): rows ty + 16*i
    float m1[8], m2[8]; int k1[8];
    #pragma unroll
    for (int i = 0; i < 8; ++i) { m1[i] = 3.4e38f; m2[i] = 3.4e38f; k1[i] = 0; }

    const float2* emb2 = (const float2*)emb;

    for (int kc = 0; kc < 4; ++kc) {
        __syncthreads();   // protect es/ee_s from previous chunk readers (covers xx_s on kc=0)
        #pragma unroll
        for (int it = 0; it < 16; ++it) {
            int idx = it * 256 + t;
            int r = idx >> 5, c2 = idx & 31;
            float2 v = emb2[(size_t)(kc * CHUNK + r) * 32 + c2];
            *(float2*)&es[r * P + 2 * c2] = v;
        }
        __syncthreads();
        if (t < CHUNK) {
            float s = 0.f;
            #pragma unroll
            for (int d = 0; d < 64; ++d) { float v = es[t * P + d]; s = fmaf(v, v, s); }
            ee_s[t] = s;
        }
        __syncthreads();

        // ---- register-tiled dot products: 8n x 8k, ds_read_b128 ----
        float acc[8][8];
        #pragma unroll
        for (int i = 0; i < 8; ++i)
            #pragma unroll
            for (int j = 0; j < 8; ++j) acc[i][j] = 0.f;

        #pragma unroll 2
        for (int d = 0; d < 64; d += 4) {
            float4 xv[8], ev[8];
            #pragma unroll
            for (int i = 0; i < 8; ++i) xv[i] = *(const float4*)&xs[(ty + 16 * i) * P + d];
            #pragma unroll
            for (int j = 0; j < 8; ++j) ev[j] = *(const float4*)&es[(tx + 16 * j) * P + d];
            #pragma unroll
            for (int i = 0; i < 8; ++i)
                #pragma unroll
                for (int j = 0; j < 8; ++j) {
                    acc[i][j] = fmaf(xv[i].x, ev[j].x, acc[i][j]);
                    acc[i][j] = fmaf(xv[i].y, ev[j].y, acc[i][j]);
                    acc[i][j] = fmaf(xv[i].z, ev[j].z, acc[i][j]);
                    acc[i][j] = fmaf(xv[i].w, ev[j].w, acc[i][j]);
                }
        }

        // ---- finalize distances + store + fused (min1,min2) tracking ----
        #pragma unroll
        for (int i = 0; i < 8; ++i) {
            int row = ty + 16 * i;
            float xxv = xx_s[row];
            float* drow = out_dist + (size_t)(n_base + row) * KCB + kc * CHUNK;
            #pragma unroll
            for (int j = 0; j < 8; ++j) {
                int kl = tx + 16 * j;
                float dist = (xxv + ee_s[kl]) - 2.f * acc[i][j];
                drow[kl] = dist;
                int kg = kc * CHUNK + kl;      // k ascending over (kc, j) => first-min tie-break
                if (dist < m1[i]) { m2[i] = m1[i]; m1[i] = dist; k1[i] = kg; }
                else if (dist < m2[i]) m2[i] = dist;
            }
        }
    }

    // ---- per-row argmin across 16 k-lanes + rare fp64 refinement (no dist re-read) ----
    {
        const int lane = t & 63;
        const unsigned long long gmask = 0xFFFFull << ((lane >> 4) * 16);
        #pragma unroll 1
        for (int i = 0; i < 8; ++i) {
            int row = ty + 16 * i;
            float bv = m1[i]; int bk = k1[i];
            #pragma unroll
            for (int m = 1; m < 16; m <<= 1) {
                float ov = __shfl_xor(bv, m, 64);
                int   ok = __shfl_xor(bk, m, 64);
                if (ov < bv || (ov == bv && ok < bk)) { bv = ov; bk = ok; }
            }
            float thr = bv + EPS;
            unsigned long long b1 = __ballot(m1[i] <= thr);
            unsigned long long b2 = __ballot(m2[i] <= thr);
            int enc = bk;
            if (__popcll(b1 & gmask) > 1 || (b2 & gmask) != 0ULL) {
                // rare: >=2 candidates within EPS -> exact fp64 over flagged lanes' 32 ks
                bool active = (m1[i] <= thr) || (m2[i] <= thr);
                double bestv = 1e300; int bestk = 0x7fffffff;
                if (active) {
                    #pragma unroll 1
                    for (int kc = 0; kc < 4; ++kc)
                        #pragma unroll 1
                        for (int j = 0; j < 8; ++j) {
                            int k = kc * CHUNK + tx + 16 * j;
                            double s = 0.0;
                            #pragma unroll 1
                            for (int d = 0; d < 64; ++d) {
                                double df = (double)xs[row * P + d] - (double)emb[k * 64 + d];
                                s += df * df;
                            }
                            if (s < bestv) { bestv = s; bestk = k; }  // ascending k, strict <
                        }
                }
                #pragma unroll
                for (int m = 1; m < 16; m <<= 1) {
                    double ov = __shfl_xor(bestv, m, 64);
                    int   ok  = __shfl_xor(bestk, m, 64);
                    if (ov < bestv || (ov == bestv && ok < bestk)) { bestv = ov; bestk = ok; }
                }
                enc = bestk;
            }
            if (tx == 0) {
                enc_s[row] = enc;
                out_enc[n_base + row] = (float)enc;
            }
        }
    }
    __syncthreads();

    // ---- quantized gather + commitment loss ----
    {
        const int w   = t & 63;
        const int hh  = (t >> 6) & 1;
        const int dg  = t >> 7;            // 0..1, 32 d each
        const int row = hh * 64 + w;
        const int e   = enc_s[row];
        const float* erow = emb + e * 64;
        const size_t qb = xb0 + hh * 64 + w;
        float lsum = 0.f;
        #pragma unroll
        for (int di = 0; di < 32; ++di) {
            int d = dg * 32 + di;
            float qv = erow[d];                       // gather, L2-resident codebook
            out_q[qb + (size_t)d * 4096] = qv;        // coalesced store
            float diff = qv - xs[row * P + d];
            lsum = fmaf(diff, diff, lsum);
        }
        #pragma unroll
        for (int m = 32; m >= 1; m >>= 1) lsum += __shfl_down(lsum, m, 64);
        if ((t & 63) == 0) red_s[t >> 6] = lsum;
    }
    __syncthreads();
    if (t == 0) {
        float tot = red_s[0] + red_s[1] + red_s[2] + red_s[3];
        atomicAdd(out_loss, tot * (1.0f / 8388608.0f));
    }
}

extern "C" void kernel_launch(void* const* d_in, const int* in_sizes, int n_in,
                              void* d_out, int out_size, void* d_ws, size_t ws_size,
                              hipStream_t stream) {
    const float* x   = (const float*)d_in[0];   // [32,64,64,64]
    const float* emb = (const float*)d_in[1];   // [512,64]

    float* out_q    = (float*)d_out;            // 8388608
    float* out_enc  = out_q + 8388608;          // 131072
    float* out_dist = out_enc + 131072;         // 67108864
    float* out_loss = out_dist + 67108864;      // 1

    hipMemsetAsync(out_loss, 0, sizeof(float), stream);
    vq_kernel<<<1024, 256, 0, stream>>>(x, emb, out_q, out_enc, out_dist, out_loss);
}